// Round 9
// baseline (261.472 us; speedup 1.0000x reference)
//
#include <hip/hip_runtime.h>

// ---------- constants ----------
#define BATCH 4
#define SEQ   2048
#define NHEAD 8
#define DQKV  64
#define DMODEL 512
#define ROWS  (BATCH*SEQ)          // 8192
#define BH    (BATCH*NHEAD)        // 32
#define HSTRIDE (SEQ*DQKV)         // 131072 elements per (b,h)

using f32x4  = __attribute__((ext_vector_type(4))) float;
using short8 = __attribute__((ext_vector_type(8))) short;
using short4v = __attribute__((ext_vector_type(4))) short;

#define MFMA16(a,b,c) __builtin_amdgcn_mfma_f32_16x16x32_bf16((a),(b),(c),0,0,0)

__device__ __forceinline__ short f2bf(float f) {
    unsigned u = __float_as_uint(f);
    u += 0x7FFFu + ((u >> 16) & 1u);
    return (short)(u >> 16);
}

// load 8 f32, convert to bf16x8 (for f32 A-operand rows in proj)
__device__ __forceinline__ short8 cvt8(const float* p) {
    float4 a = *(const float4*)p;
    float4 b = *(const float4*)(p + 4);
    short8 o;
    o[0]=f2bf(a.x); o[1]=f2bf(a.y); o[2]=f2bf(a.z); o[3]=f2bf(a.w);
    o[4]=f2bf(b.x); o[5]=f2bf(b.y); o[6]=f2bf(b.z); o[7]=f2bf(b.w);
    return o;
}

// async global->LDS 16B DMA (LDS dst = waveBase + lane*16)
__device__ __forceinline__ void gl2lds16(const short* g, short* l) {
    __builtin_amdgcn_global_load_lds(
        (__attribute__((address_space(1))) void*)g,
        (__attribute__((address_space(3))) void*)l, 16, 0, 0);
}

// stage a 64-row x 64-short tile (8KB), XOR chunk-swizzled, via DMA.
// swizzle applied in GLOBAL source so LDS write order stays linear.
__device__ __forceinline__ void stage64x64(const short* g0, int gstride, short* lt, int t) {
    #pragma unroll
    for (int p = 0; p < 2; ++p) {
        int o = p * 2048 + t * 8;          // shorts; per-lane 16B, linear
        int row = o >> 6;
        int c = ((o >> 3) & 7) ^ (row & 7);
        gl2lds16(g0 + (size_t)row * gstride + c * 8, lt + o);
    }
}
// 128-row variant (16KB)
__device__ __forceinline__ void stage128x64(const short* g0, int gstride, short* lt, int t) {
    stage64x64(g0, gstride, lt, t);
    stage64x64(g0 + (size_t)64 * gstride, gstride, lt + 4096, t);
}

// read logical 16B chunk (row, c) from a swizzled 64-short-stride tile
__device__ __forceinline__ short8 trd(const short* t, int row, int c) {
    return *(const short8*)(t + row * 64 + ((c ^ (row & 7)) << 3));
}

// ---------- fused prep: maskpack | LN(q) | W transpose-cast ----------
// (k/v bf16 casting removed: proj_qkv reads k,v f32 directly)
// 1-D grid, block ranges:
//   [0,4096)     maskpack (long pole: 67 MB mask read) -> starts first
//   [4096,6144)  LayerNorm(q) -> bf16
//   [6144,6400)  W[k][n] -> Wt[n][k] bf16 (4 weights, 64x64 tiles)
__global__ __launch_bounds__(256) void prep_all_kernel(
        const float* __restrict__ q, const float* __restrict__ gamma,
        const float* __restrict__ beta, const int* __restrict__ mask,
        const float* __restrict__ W0in, const float* __restrict__ W1in,
        const float* __restrict__ W2in, const float* __restrict__ W3in,
        short* __restrict__ qn, unsigned long long* __restrict__ mp,
        short* __restrict__ T0, short* __restrict__ T1,
        short* __restrict__ T2, short* __restrict__ T3) {
    __shared__ short tile[64 * 68];
    int bid = blockIdx.x;
    int tid = threadIdx.x;
    if (bid < 4096) {
        // ---- maskpack: word idx = (((b*128+Qg)*32+w64)*4+kg)*4+r,
        //      bit l (=16*lg+lm) = mask[Qg*16+lm][w64*64+kg*16+lg*4+r]
        int gw = bid * 4 + (tid >> 6);
        int lane = tid & 63;
        int lm = lane & 15, lg = lane >> 4;
        int w64 = gw & 31;
        int Qg  = (gw >> 5) & 127;
        int b   = gw >> 12;
        const int* src = mask + ((size_t)b * SEQ + Qg * 16 + lm) * SEQ + w64 * 64 + lg * 4;
        unsigned long long* d = mp + (size_t)gw * 16;
        #pragma unroll
        for (int kg = 0; kg < 4; ++kg) {
            int4 vv = *(const int4*)(src + kg * 16);
            unsigned long long w0 = __ballot(vv.x != 0);
            unsigned long long w1 = __ballot(vv.y != 0);
            unsigned long long w2 = __ballot(vv.z != 0);
            unsigned long long w3 = __ballot(vv.w != 0);
            if (lane == 0) {
                *(ulonglong2*)(d + kg*4)     = make_ulonglong2(w0, w1);
                *(ulonglong2*)(d + kg*4 + 2) = make_ulonglong2(w2, w3);
            }
        }
    } else if (bid < 6144) {
        // ---- LayerNorm(q) -> bf16, one row per wave
        int wave = tid >> 6, lane = tid & 63;
        int row  = (bid - 4096) * 4 + wave;
        const float4* qr = (const float4*)(q + (size_t)row * DMODEL);
        float4 x0 = qr[lane * 2];
        float4 x1 = qr[lane * 2 + 1];
        float s  = x0.x + x0.y + x0.z + x0.w + x1.x + x1.y + x1.z + x1.w;
        float s2 = x0.x*x0.x + x0.y*x0.y + x0.z*x0.z + x0.w*x0.w
                 + x1.x*x1.x + x1.y*x1.y + x1.z*x1.z + x1.w*x1.w;
        #pragma unroll
        for (int m = 1; m < 64; m <<= 1) {
            s  += __shfl_xor(s,  m);
            s2 += __shfl_xor(s2, m);
        }
        float mu  = s * (1.0f / DMODEL);
        float var = s2 * (1.0f / DMODEL) - mu * mu;
        float rstd = rsqrtf(var + 1e-6f);
        const float4* g = (const float4*)gamma;
        const float4* be = (const float4*)beta;
        float4 g0 = g[lane*2], g1 = g[lane*2+1];
        float4 b0 = be[lane*2], b1 = be[lane*2+1];
        short8 o;
        o[0] = f2bf((x0.x - mu) * rstd * g0.x + b0.x);
        o[1] = f2bf((x0.y - mu) * rstd * g0.y + b0.y);
        o[2] = f2bf((x0.z - mu) * rstd * g0.z + b0.z);
        o[3] = f2bf((x0.w - mu) * rstd * g0.w + b0.w);
        o[4] = f2bf((x1.x - mu) * rstd * g1.x + b1.x);
        o[5] = f2bf((x1.y - mu) * rstd * g1.y + b1.y);
        o[6] = f2bf((x1.z - mu) * rstd * g1.z + b1.z);
        o[7] = f2bf((x1.w - mu) * rstd * g1.w + b1.w);
        ((short8*)(qn + (size_t)row * DMODEL))[lane] = o;
    } else {
        // ---- W transpose-cast: 64x64 tile per block
        int b4 = bid - 6144;           // [0,256)
        int w = b4 >> 6, ti = (b4 >> 3) & 7, tj = b4 & 7;
        const float* W = w==0 ? W0in : w==1 ? W1in : w==2 ? W2in : W3in;
        short* T = w==0 ? T0 : w==1 ? T1 : w==2 ? T2 : T3;
        #pragma unroll
        for (int p = 0; p < 4; ++p) {
            int idx = tid + p * 256;
            int kl = idx >> 4, c4 = idx & 15;
            float4 f = *(const float4*)(W + (size_t)(tj*64 + kl) * DMODEL + ti*64 + c4*4);
            short4v sv; sv[0]=f2bf(f.x); sv[1]=f2bf(f.y); sv[2]=f2bf(f.z); sv[3]=f2bf(f.w);
            *(short4v*)(tile + kl*68 + c4*4) = sv;
        }
        __syncthreads();
        #pragma unroll
        for (int p = 0; p < 4; ++p) {
            int idx = tid + p * 256;
            int nl = idx >> 4, kseg = idx & 15;
            short4v sv;
            #pragma unroll
            for (int i = 0; i < 4; ++i) sv[i] = tile[(kseg*4 + i)*68 + nl];
            *(short4v*)(T + (size_t)(ti*64 + nl) * DMODEL + tj*64 + kseg*4) = sv;
        }
    }
}

// ---------- fused QKV projection: 128x128 tiles, DMA-swizzled W, V^T output ----------
// A-operand: q from qn (bf16, LayerNorm'd), k/v read DIRECTLY as f32 + in-reg cvt
// (removes the 48MB-read/16MB-write bf16 round-trip in prep).
// V^T stored in PV-fragment order: within each 64-key block,
//   key k = 32a+16h+4g+r  ->  pos = 32a+8g+4h+r
// so attn's PV B-operand is ONE contiguous 16B chunk per lane (b128, conflict-free).
__global__ __launch_bounds__(256, 4) void proj_qkv_kernel(
        const short* __restrict__ qn, const float* __restrict__ kf,
        const float* __restrict__ vf,
        const short* __restrict__ Wqt, const short* __restrict__ Wkt,
        const short* __restrict__ Wvt,
        short* __restrict__ qhp, short* __restrict__ khp, short* __restrict__ vtp) {
    __shared__ __align__(16) short Wl[2 * 8192];     // 32 KB
    int tid = threadIdx.x, wave = tid >> 6, lane = tid & 63;
    int lm = lane & 15, lg = lane >> 4;
    int which = blockIdx.y >> 2;
    int CB0 = (blockIdx.y & 3) * 128;
    const short* Wt = which==0 ? Wqt : which==1 ? Wkt : Wvt;
    // Q gets 1/sqrt(64) * log2(e) folded in (attention uses exp2)
    float scale = which==0 ? 0.18033688f : 1.0f;

    int RBw = blockIdx.x * 128 + wave * 32;
    const short* Aq0 = qn + (size_t)(RBw + lm) * DMODEL;
    const short* Aq1 = qn + (size_t)(RBw + 16 + lm) * DMODEL;
    const float* Af  = which==1 ? kf : vf;
    const float* Af0 = Af + (size_t)(RBw + lm) * DMODEL;
    const float* Af1 = Af + (size_t)(RBw + 16 + lm) * DMODEL;
    const short* W0 = Wt + (size_t)CB0 * DMODEL;

    short8 a[2][2];
    if (which == 0) {
        a[0][0] = *(const short8*)(Aq0 + lg * 8);
        a[0][1] = *(const short8*)(Aq0 + 32 + lg * 8);
        a[1][0] = *(const short8*)(Aq1 + lg * 8);
        a[1][1] = *(const short8*)(Aq1 + 32 + lg * 8);
    } else {
        a[0][0] = cvt8(Af0 + lg * 8);
        a[0][1] = cvt8(Af0 + 32 + lg * 8);
        a[1][0] = cvt8(Af1 + lg * 8);
        a[1][1] = cvt8(Af1 + 32 + lg * 8);
    }
    stage128x64(W0, DMODEL, Wl, tid);
    __syncthreads();

    f32x4 acc[2][8] = {};
    for (int kk = 0; kk < DMODEL; kk += 64) {
        int cur = (kk >> 6) & 1;
        bool more = (kk + 64) < DMODEL;
        short8 an[2][2];
        if (more) {
            stage128x64(W0 + kk + 64, DMODEL, Wl + (cur ^ 1) * 8192, tid);
            if (which == 0) {
                an[0][0] = *(const short8*)(Aq0 + kk + 64 + lg * 8);
                an[0][1] = *(const short8*)(Aq0 + kk + 96 + lg * 8);
                an[1][0] = *(const short8*)(Aq1 + kk + 64 + lg * 8);
                an[1][1] = *(const short8*)(Aq1 + kk + 96 + lg * 8);
            } else {
                an[0][0] = cvt8(Af0 + kk + 64 + lg * 8);
                an[0][1] = cvt8(Af0 + kk + 96 + lg * 8);
                an[1][0] = cvt8(Af1 + kk + 64 + lg * 8);
                an[1][1] = cvt8(Af1 + kk + 96 + lg * 8);
            }
        }
        const short* Wc = Wl + cur * 8192;
        #pragma unroll
        for (int cg = 0; cg < 8; ++cg) {
            short8 b0 = trd(Wc, cg*16 + lm, lg);
            short8 b1 = trd(Wc, cg*16 + lm, lg + 4);
            #pragma unroll
            for (int rg = 0; rg < 2; ++rg) {
                acc[rg][cg] = MFMA16(a[rg][0], b0, acc[rg][cg]);
                acc[rg][cg] = MFMA16(a[rg][1], b1, acc[rg][cg]);
            }
        }
        if (more) {
            #pragma unroll
            for (int rg = 0; rg < 2; ++rg) { a[rg][0] = an[rg][0]; a[rg][1] = an[rg][1]; }
        }
        __syncthreads();
    }

    if (which < 2) {
        short* outh = which==0 ? qhp : khp;
        #pragma unroll
        for (int rg = 0; rg < 2; ++rg) {
            #pragma unroll
            for (int cg = 0; cg < 8; ++cg) {
                int n = CB0 + cg * 16 + lm;
                int h = n >> 6, d = n & 63;
                #pragma unroll
                for (int r = 0; r < 4; ++r) {
                    int m = RBw + rg * 16 + lg * 4 + r;
                    int bb = m >> 11, s = m & 2047;
                    outh[(size_t)(bb * NHEAD + h) * HSTRIDE + (size_t)s * DQKV + d] =
                        f2bf(acc[rg][cg][r] * scale);
                }
            }
        }
    } else {
        // V output transposed + fragment-permuted: vt[b][h][d][pos(s)]
        int bb = RBw >> 11;
        #pragma unroll
        for (int rg = 0; rg < 2; ++rg) {
            int s0 = (RBw + rg * 16 + lg * 4) & 2047;
            int s6 = s0 & 63;
            // k = 32a+16h+4g (+r) -> pos = 32a+8g+4h (+r)
            int pos = (s0 & ~63) | (s6 & 32) | ((s6 & 12) << 1) | ((s6 & 16) >> 2);
            #pragma unroll
            for (int cg = 0; cg < 8; ++cg) {
                int n = CB0 + cg * 16 + lm;
                int h = n >> 6, d = n & 63;
                short4v pk;
                #pragma unroll
                for (int r = 0; r < 4; ++r) pk[r] = f2bf(acc[rg][cg][r]);
                *(short4v*)(vtp + (size_t)(bb * NHEAD + h) * HSTRIDE
                            + (size_t)d * SEQ + pos) = pk;
            }
        }
    }
}

// ---------- flash attention v9: v8 + mid-loop barrier (PV reads hoisted) ----------
// 128 q/block (32 q/wave), swapped QK^T, in-register P, fragment-ordered V^T.
// Reorder: [stage(next) | QK reads+MFMA | PV reads] -> barrier -> [softmax | PV MFMA].
// All reads of buffer `cur` complete before the barrier; the next overwrite of
// `cur` is DMA issued after it. The barrier's compiler-emitted vmcnt(0) drain
// guarantees `nxt` staging is complete before the next iteration reads it.
// Post-barrier VALU/MFMA overlaps other waves' next-iter LDS reads.
// NOTE: setprio around MFMA measured -20% here (r7) — barrier-lockstep waves
// are the m190 regime, not m191's; do not re-add.
__global__ __launch_bounds__(256, 2) void attn_kernel(
        const short* __restrict__ qh, const short* __restrict__ kh,
        const short* __restrict__ vt, const unsigned long long* __restrict__ mpack,
        short* __restrict__ oh) {
    __shared__ __align__(16) short lds[16384];   // 32 KB
    int tid = threadIdx.x, wave = tid >> 6, lane = tid & 63;
    int lm = lane & 15, lg = lane >> 4;

    // XCD-partition remap: all 512 blocks resident (2/CU); give each XCD 4 bh
    // so its K/V working set (4 x 512 KB = 2 MB) fits the 4 MB per-XCD L2.
    int bid = blockIdx.y * gridDim.x + blockIdx.x;
    int slot = bid >> 3;
    int bh = (bid & 7) * 4 + (slot >> 4);
    int qt = slot & 15;
    int b = bh >> 3;
    int qbase = qt * 128 + wave * 32;

    const short* Kbase = kh + (size_t)bh * HSTRIDE;
    const short* Vtb   = vt + (size_t)bh * HSTRIDE;

    const short8* Qrow = (const short8*)(qh + (size_t)bh * HSTRIDE
                          + (size_t)(qbase + lm) * DQKV);
    short8 aq[2][2];
    aq[0][0] = Qrow[lg];       aq[0][1] = Qrow[lg + 4];
    aq[1][0] = Qrow[128 + lg]; aq[1][1] = Qrow[128 + lg + 4];   // +16 rows

    // wave-uniform mask base: Qg0 = qbase/16 = qt*8 + wave*2
    int mb = __builtin_amdgcn_readfirstlane((b * 128 + qt * 8 + wave * 2) * 512);
    const unsigned long long* mbase = mpack + mb;

    const short one = (short)0x3F80;   // bf16 1.0
    short8 ones8 = {one, one, one, one, one, one, one, one};

    f32x4 o[2][4] = {};
    f32x4 ox[2] = {};

    // prologue: stage tile 0
    stage64x64(Kbase, DQKV, lds, tid);
    stage64x64(Vtb,   SEQ,  lds + 8192, tid);
    __syncthreads();

    for (int kt = 0; kt < SEQ; kt += 64) {
        int cur = (kt >> 6) & 1;
        if (kt + 64 < SEQ) {
            int nxt = cur ^ 1;
            stage64x64(Kbase + (size_t)(kt + 64) * DQKV, DQKV, lds + nxt * 4096, tid);
            stage64x64(Vtb + kt + 64, SEQ, lds + 8192 + nxt * 4096, tid);
        }
        const short* Kc = lds + cur * 4096;
        const short* Vc = lds + 8192 + cur * 4096;
        const unsigned long long* mw = mbase + (kt >> 6) * 16;

        // ---- S^T = K Q^T : sk[qg][kg][r] = S[qbase+qg*16+lm][kt+kg*16+lg*4+r] ----
        f32x4 sk[2][4];
        #pragma unroll
        for (int kg = 0; kg < 4; ++kg) {
            short8 ak0 = trd(Kc, kg * 16 + lm, lg);
            short8 ak1 = trd(Kc, kg * 16 + lm, lg + 4);
            #pragma unroll
            for (int qg = 0; qg < 2; ++qg) {
                f32x4 z{};
                z = MFMA16(ak0, aq[qg][0], z);
                sk[qg][kg] = MFMA16(ak1, aq[qg][1], z);
            }
        }

        // ---- PV B-operand reads (last reads of `cur`) ----
        short8 bvr[8];
        #pragma unroll
        for (int dt = 0; dt < 4; ++dt) {
            #pragma unroll
            for (int kgp = 0; kgp < 2; ++kgp)
                bvr[dt * 2 + kgp] = trd(Vc, dt * 16 + lm, kgp * 4 + lg);
        }

        __syncthreads();   // mid-loop: drains stage DMA; frees `cur` for overwrite

        // ---- masked exp2 -> packed bf16 A-fragments (pure registers) ----
        // pa8[qg][kgp][jj] = P[q=lm][key = kgp*32 + (jj<4 ? lg*4+jj : 16+lg*4+jj-4)]
        short8 pa8[2][2];
        #pragma unroll
        for (int qg = 0; qg < 2; ++qg) {
            #pragma unroll
            for (int kgp = 0; kgp < 2; ++kgp) {
                float p[8];
                #pragma unroll
                for (int jj = 0; jj < 8; ++jj) {
                    int kg = kgp * 2 + (jj >> 2), r = jj & 3;
                    unsigned long long mword = mw[qg * 512 + kg * 4 + r];
                    float e = __builtin_amdgcn_exp2f(sk[qg][kg][r]);
                    asm("v_cndmask_b32 %0, 0, %1, %2" : "=v"(p[jj]) : "v"(e), "s"(mword));
                }
                int w0, w1, w2, w3;
                asm("v_cvt_pk_bf16_f32 %0, %1, %2" : "=v"(w0) : "v"(p[0]), "v"(p[1]));
                asm("v_cvt_pk_bf16_f32 %0, %1, %2" : "=v"(w1) : "v"(p[2]), "v"(p[3]));
                asm("v_cvt_pk_bf16_f32 %0, %1, %2" : "=v"(w2) : "v"(p[4]), "v"(p[5]));
                asm("v_cvt_pk_bf16_f32 %0, %1, %2" : "=v"(w3) : "v"(p[6]), "v"(p[7]));
                union { int wi[4]; short8 s; } u;
                u.wi[0] = w0; u.wi[1] = w1; u.wi[2] = w2; u.wi[3] = w3;
                pa8[qg][kgp] = u.s;
            }
        }

        // ---- O += P V  (register-resident B fragments) ----
        #pragma unroll
        for (int dt = 0; dt < 4; ++dt) {
            #pragma unroll
            for (int kgp = 0; kgp < 2; ++kgp) {
                o[0][dt] = MFMA16(pa8[0][kgp], bvr[dt * 2 + kgp], o[0][dt]);
                o[1][dt] = MFMA16(pa8[1][kgp], bvr[dt * 2 + kgp], o[1][dt]);
            }
        }
        // rowsum via constant all-ones B fragment (every output col = rowsum)
        #pragma unroll
        for (int qg = 0; qg < 2; ++qg) {
            ox[qg] = MFMA16(pa8[qg][0], ones8, ox[qg]);
            ox[qg] = MFMA16(pa8[qg][1], ones8, ox[qg]);
        }
    }

    // epilogue: normalize, store bf16
    short* ob = oh + (size_t)bh * HSTRIDE;
    #pragma unroll
    for (int qg = 0; qg < 2; ++qg) {
        float rinv[4];
        #pragma unroll
        for (int r = 0; r < 4; ++r) rinv[r] = __builtin_amdgcn_rcpf(ox[qg][r]);
        #pragma unroll
        for (int dt = 0; dt < 4; ++dt) {
            #pragma unroll
            for (int r = 0; r < 4; ++r) {
                ob[(size_t)(qbase + qg * 16 + lg * 4 + r) * DQKV + dt * 16 + lm] =
                    f2bf(o[qg][dt][r] * rinv[r]);
            }
        }
    }
}

// ---------- output projection + residual: 128x64 tiles (32 rows/wave) ----------
__global__ __launch_bounds__(256, 4) void outproj_kernel(
        const short* __restrict__ Ah, const short* __restrict__ Wfct,
        const float* __restrict__ resid, float* __restrict__ out) {
    __shared__ __align__(16) short Wl[2 * 4096];    // 16 KB
    int tid = threadIdx.x, wave = tid >> 6, lane = tid & 63;
    int lm = lane & 15, lg = lane >> 4;
    int CB0 = blockIdx.y * 64;
    int RB = blockIdx.x * 128 + wave * 32;
    const short* W0 = Wfct + (size_t)CB0 * DMODEL;

    int m0 = RB + lm, m1 = RB + 16 + lm;
    size_t rb0 = (size_t)(m0 >> 11) * (NHEAD * HSTRIDE) + (size_t)(m0 & 2047) * DQKV;
    size_t rb1 = (size_t)(m1 >> 11) * (NHEAD * HSTRIDE) + (size_t)(m1 & 2047) * DQKV;

    short8 a[2][2];
    a[0][0] = *(const short8*)(Ah + rb0 + lg * 8);
    a[0][1] = *(const short8*)(Ah + rb0 + 32 + lg * 8);
    a[1][0] = *(const short8*)(Ah + rb1 + lg * 8);
    a[1][1] = *(const short8*)(Ah + rb1 + 32 + lg * 8);
    stage64x64(W0, DMODEL, Wl, tid);
    __syncthreads();

    f32x4 acc[2][4] = {};
    for (int kk = 0; kk < DMODEL; kk += 64) {
        int cur = (kk >> 6) & 1;
        bool more = (kk + 64) < DMODEL;
        short8 an[2][2];
        if (more) {
            stage64x64(W0 + kk + 64, DMODEL, Wl + (cur ^ 1) * 4096, tid);
            size_t hoff = (size_t)((kk >> 6) + 1) * HSTRIDE;
            an[0][0] = *(const short8*)(Ah + rb0 + hoff + lg * 8);
            an[0][1] = *(const short8*)(Ah + rb0 + hoff + 32 + lg * 8);
            an[1][0] = *(const short8*)(Ah + rb1 + hoff + lg * 8);
            an[1][1] = *(const short8*)(Ah + rb1 + hoff + 32 + lg * 8);
        }
        const short* Wc = Wl + cur * 4096;
        #pragma unroll
        for (int cg = 0; cg < 4; ++cg) {
            short8 b0 = trd(Wc, cg*16 + lm, lg);
            short8 b1 = trd(Wc, cg*16 + lm, lg + 4);
            #pragma unroll
            for (int rg = 0; rg < 2; ++rg) {
                acc[rg][cg] = MFMA16(a[rg][0], b0, acc[rg][cg]);
                acc[rg][cg] = MFMA16(a[rg][1], b1, acc[rg][cg]);
            }
        }
        if (more) {
            #pragma unroll
            for (int rg = 0; rg < 2; ++rg) { a[rg][0] = an[rg][0]; a[rg][1] = an[rg][1]; }
        }
        __syncthreads();
    }

    #pragma unroll
    for (int rg = 0; rg < 2; ++rg) {
        #pragma unroll
        for (int cg = 0; cg < 4; ++cg) {
            int n = CB0 + cg * 16 + lm;
            #pragma unroll
            for (int r = 0; r < 4; ++r) {
                int m = RB + rg * 16 + lg * 4 + r;
                size_t idx = (size_t)m * DMODEL + n;
                out[idx] = acc[rg][cg][r] + resid[idx];
            }
        }
    }
}

// ---------- host launch ----------
extern "C" void kernel_launch(void* const* d_in, const int* in_sizes, int n_in,
                              void* d_out, int out_size, void* d_ws, size_t ws_size,
                              hipStream_t stream) {
    const float* q     = (const float*)d_in[0];
    const float* k     = (const float*)d_in[1];
    const float* v     = (const float*)d_in[2];
    const int*   mask  = (const int*)d_in[3];
    const float* Wq    = (const float*)d_in[4];
    const float* Wk    = (const float*)d_in[5];
    const float* Wv    = (const float*)d_in[6];
    const float* Wfc   = (const float*)d_in[7];
    const float* gamma = (const float*)d_in[8];
    const float* beta  = (const float*)d_in[9];
    float* out = (float*)d_out;

    char* ws = (char*)d_ws;
    const size_t SZ_ROWS = (size_t)ROWS * DMODEL * sizeof(short);   // 8 MB
    const size_t SZ_W    = (size_t)DMODEL * DMODEL * sizeof(short); // 512 KB
    short* qn   = (short*)(ws);
    short* Wqt  = (short*)(ws + 3 * SZ_ROWS);
    short* Wkt  = (short*)(ws + 3 * SZ_ROWS + SZ_W);
    short* Wvt  = (short*)(ws + 3 * SZ_ROWS + 2 * SZ_W);
    short* Wfct = (short*)(ws + 3 * SZ_ROWS + 3 * SZ_W);
    short* qhb  = (short*)(ws + 3 * SZ_ROWS + 4 * SZ_W);
    short* khb  = (short*)(ws + 4 * SZ_ROWS + 4 * SZ_W);
    short* vtb  = (short*)(ws + 5 * SZ_ROWS + 4 * SZ_W);
    unsigned long long* mpack = (unsigned long long*)(ws + 6 * SZ_ROWS + 4 * SZ_W); // 2 MB
    short* aout = qn;    // qn dead after proj

    prep_all_kernel<<<dim3(6400), 256, 0, stream>>>(
        q, gamma, beta, mask, Wq, Wk, Wv, Wfc,
        qn, mpack, Wqt, Wkt, Wvt, Wfct);

    proj_qkv_kernel<<<dim3(ROWS / 128, 12), 256, 0, stream>>>(
        qn, k, v, Wqt, Wkt, Wvt, qhb, khb, vtb);

    attn_kernel<<<dim3(SEQ / 128, BH), 256, 0, stream>>>(qhb, khb, vtb, mpack, aout);

    outproj_kernel<<<dim3(ROWS / 128, DMODEL / 64), 256, 0, stream>>>(aout, Wfct, q, out);
}

// Round 12
// 243.909 us; speedup vs baseline: 1.0720x; 1.0720x over previous
//
#include <hip/hip_runtime.h>

// ---------- constants ----------
#define BATCH 4
#define SEQ   2048
#define NHEAD 8
#define DQKV  64
#define DMODEL 512
#define ROWS  (BATCH*SEQ)          // 8192
#define BH    (BATCH*NHEAD)        // 32
#define HSTRIDE (SEQ*DQKV)         // 131072 elements per (b,h)

using f32x4  = __attribute__((ext_vector_type(4))) float;
using short8 = __attribute__((ext_vector_type(8))) short;
using short4v = __attribute__((ext_vector_type(4))) short;

#define MFMA16(a,b,c) __builtin_amdgcn_mfma_f32_16x16x32_bf16((a),(b),(c),0,0,0)

__device__ __forceinline__ short f2bf(float f) {
    unsigned u = __float_as_uint(f);
    u += 0x7FFFu + ((u >> 16) & 1u);
    return (short)(u >> 16);
}

// async global->LDS 16B DMA (LDS dst = waveBase + lane*16)
__device__ __forceinline__ void gl2lds16(const short* g, short* l) {
    __builtin_amdgcn_global_load_lds(
        (__attribute__((address_space(1))) void*)g,
        (__attribute__((address_space(3))) void*)l, 16, 0, 0);
}

// stage a 64-row x 64-short tile (8KB), XOR chunk-swizzled, via DMA.
// swizzle applied in GLOBAL source so LDS write order stays linear.
__device__ __forceinline__ void stage64x64(const short* g0, int gstride, short* lt, int t) {
    #pragma unroll
    for (int p = 0; p < 2; ++p) {
        int o = p * 2048 + t * 8;          // shorts; per-lane 16B, linear
        int row = o >> 6;
        int c = ((o >> 3) & 7) ^ (row & 7);
        gl2lds16(g0 + (size_t)row * gstride + c * 8, lt + o);
    }
}
// 128-row variant (16KB)
__device__ __forceinline__ void stage128x64(const short* g0, int gstride, short* lt, int t) {
    stage64x64(g0, gstride, lt, t);
    stage64x64(g0 + (size_t)64 * gstride, gstride, lt + 4096, t);
}

// read logical 16B chunk (row, c) from a swizzled 64-short-stride tile
__device__ __forceinline__ short8 trd(const short* t, int row, int c) {
    return *(const short8*)(t + row * 64 + ((c ^ (row & 7)) << 3));
}

// ---------- fused prep: maskpack | cast k/v | LN(q) | W transpose-cast ----------
// 1-D grid, block ranges:
//   [0,4096)      maskpack (long pole: 67 MB mask read) -> starts first
//   [4096,8192)   cast k (first 2048) / v (next 2048) -> bf16
//   [8192,10240)  LayerNorm(q) -> bf16
//   [10240,10496) W[k][n] -> Wt[n][k] bf16 (4 weights, 64x64 tiles)
__global__ __launch_bounds__(256) void prep_all_kernel(
        const float* __restrict__ q, const float* __restrict__ k,
        const float* __restrict__ v, const float* __restrict__ gamma,
        const float* __restrict__ beta, const int* __restrict__ mask,
        const float* __restrict__ W0in, const float* __restrict__ W1in,
        const float* __restrict__ W2in, const float* __restrict__ W3in,
        short* __restrict__ qn, short* __restrict__ kb, short* __restrict__ vb,
        unsigned long long* __restrict__ mp,
        short* __restrict__ T0, short* __restrict__ T1,
        short* __restrict__ T2, short* __restrict__ T3) {
    __shared__ short tile[64 * 68];
    int bid = blockIdx.x;
    int tid = threadIdx.x;
    if (bid < 4096) {
        // ---- maskpack: word idx = (((b*128+Qg)*32+w64)*4+kg)*4+r,
        //      bit l (=16*lg+lm) = mask[Qg*16+lm][w64*64+kg*16+lg*4+r]
        int gw = bid * 4 + (tid >> 6);
        int lane = tid & 63;
        int lm = lane & 15, lg = lane >> 4;
        int w64 = gw & 31;
        int Qg  = (gw >> 5) & 127;
        int b   = gw >> 12;
        const int* src = mask + ((size_t)b * SEQ + Qg * 16 + lm) * SEQ + w64 * 64 + lg * 4;
        unsigned long long* d = mp + (size_t)gw * 16;
        #pragma unroll
        for (int kg = 0; kg < 4; ++kg) {
            int4 vv = *(const int4*)(src + kg * 16);
            unsigned long long w0 = __ballot(vv.x != 0);
            unsigned long long w1 = __ballot(vv.y != 0);
            unsigned long long w2 = __ballot(vv.z != 0);
            unsigned long long w3 = __ballot(vv.w != 0);
            if (lane == 0) {
                *(ulonglong2*)(d + kg*4)     = make_ulonglong2(w0, w1);
                *(ulonglong2*)(d + kg*4 + 2) = make_ulonglong2(w2, w3);
            }
        }
    } else if (bid < 8192) {
        // ---- cast k / v -> bf16
        int b2 = bid - 4096;
        const float* src = (b2 < 2048) ? k : v;
        short* dst = (b2 < 2048) ? kb : vb;
        size_t i = (size_t)(b2 & 2047) * 2048 + (size_t)tid * 8;
        float4 a = *(const float4*)(src + i);
        float4 c = *(const float4*)(src + i + 4);
        short8 o;
        o[0]=f2bf(a.x); o[1]=f2bf(a.y); o[2]=f2bf(a.z); o[3]=f2bf(a.w);
        o[4]=f2bf(c.x); o[5]=f2bf(c.y); o[6]=f2bf(c.z); o[7]=f2bf(c.w);
        *(short8*)(dst + i) = o;
    } else if (bid < 10240) {
        // ---- LayerNorm(q) -> bf16, one row per wave
        int wave = tid >> 6, lane = tid & 63;
        int row  = (bid - 8192) * 4 + wave;
        const float4* qr = (const float4*)(q + (size_t)row * DMODEL);
        float4 x0 = qr[lane * 2];
        float4 x1 = qr[lane * 2 + 1];
        float s  = x0.x + x0.y + x0.z + x0.w + x1.x + x1.y + x1.z + x1.w;
        float s2 = x0.x*x0.x + x0.y*x0.y + x0.z*x0.z + x0.w*x0.w
                 + x1.x*x1.x + x1.y*x1.y + x1.z*x1.z + x1.w*x1.w;
        #pragma unroll
        for (int m = 1; m < 64; m <<= 1) {
            s  += __shfl_xor(s,  m);
            s2 += __shfl_xor(s2, m);
        }
        float mu  = s * (1.0f / DMODEL);
        float var = s2 * (1.0f / DMODEL) - mu * mu;
        float rstd = rsqrtf(var + 1e-6f);
        const float4* g = (const float4*)gamma;
        const float4* be = (const float4*)beta;
        float4 g0 = g[lane*2], g1 = g[lane*2+1];
        float4 b0 = be[lane*2], b1 = be[lane*2+1];
        short8 o;
        o[0] = f2bf((x0.x - mu) * rstd * g0.x + b0.x);
        o[1] = f2bf((x0.y - mu) * rstd * g0.y + b0.y);
        o[2] = f2bf((x0.z - mu) * rstd * g0.z + b0.z);
        o[3] = f2bf((x0.w - mu) * rstd * g0.w + b0.w);
        o[4] = f2bf((x1.x - mu) * rstd * g1.x + b1.x);
        o[5] = f2bf((x1.y - mu) * rstd * g1.y + b1.y);
        o[6] = f2bf((x1.z - mu) * rstd * g1.z + b1.z);
        o[7] = f2bf((x1.w - mu) * rstd * g1.w + b1.w);
        ((short8*)(qn + (size_t)row * DMODEL))[lane] = o;
    } else {
        // ---- W transpose-cast: 64x64 tile per block
        int b4 = bid - 10240;          // [0,256)
        int w = b4 >> 6, ti = (b4 >> 3) & 7, tj = b4 & 7;
        const float* W = w==0 ? W0in : w==1 ? W1in : w==2 ? W2in : W3in;
        short* T = w==0 ? T0 : w==1 ? T1 : w==2 ? T2 : T3;
        #pragma unroll
        for (int p = 0; p < 4; ++p) {
            int idx = tid + p * 256;
            int kl = idx >> 4, c4 = idx & 15;
            float4 f = *(const float4*)(W + (size_t)(tj*64 + kl) * DMODEL + ti*64 + c4*4);
            short4v sv; sv[0]=f2bf(f.x); sv[1]=f2bf(f.y); sv[2]=f2bf(f.z); sv[3]=f2bf(f.w);
            *(short4v*)(tile + kl*68 + c4*4) = sv;
        }
        __syncthreads();
        #pragma unroll
        for (int p = 0; p < 4; ++p) {
            int idx = tid + p * 256;
            int nl = idx >> 4, kseg = idx & 15;
            short4v sv;
            #pragma unroll
            for (int i = 0; i < 4; ++i) sv[i] = tile[(kseg*4 + i)*68 + nl];
            *(short4v*)(T + (size_t)(ti*64 + nl) * DMODEL + tj*64 + kseg*4) = sv;
        }
    }
}

// ---------- fused QKV projection: 128x128 tiles, DMA-swizzled W, V^T output ----------
// V^T stored in PV-fragment order: within each 64-key block,
//   key k = 32a+16h+4g+r  ->  pos = 32a+8g+4h+r
// so attn's PV B-operand is ONE contiguous 16B chunk per lane (b128, conflict-free).
__global__ __launch_bounds__(256, 4) void proj_qkv_kernel(
        const short* __restrict__ qn, const short* __restrict__ kb,
        const short* __restrict__ vb,
        const short* __restrict__ Wqt, const short* __restrict__ Wkt,
        const short* __restrict__ Wvt,
        short* __restrict__ qhp, short* __restrict__ khp, short* __restrict__ vtp) {
    __shared__ __align__(16) short Wl[2 * 8192];     // 32 KB
    int tid = threadIdx.x, wave = tid >> 6, lane = tid & 63;
    int lm = lane & 15, lg = lane >> 4;
    int which = blockIdx.y >> 2;
    int CB0 = (blockIdx.y & 3) * 128;
    const short* A  = which==0 ? qn  : which==1 ? kb  : vb;
    const short* Wt = which==0 ? Wqt : which==1 ? Wkt : Wvt;
    // Q gets 1/sqrt(64) * log2(e) folded in (attention uses exp2)
    float scale = which==0 ? 0.18033688f : 1.0f;

    int RBw = blockIdx.x * 128 + wave * 32;
    const short* Arow0 = A + (size_t)(RBw + lm) * DMODEL;
    const short* Arow1 = A + (size_t)(RBw + 16 + lm) * DMODEL;
    const short* W0 = Wt + (size_t)CB0 * DMODEL;

    short8 a[2][2];
    a[0][0] = *(const short8*)(Arow0 + lg * 8);
    a[0][1] = *(const short8*)(Arow0 + 32 + lg * 8);
    a[1][0] = *(const short8*)(Arow1 + lg * 8);
    a[1][1] = *(const short8*)(Arow1 + 32 + lg * 8);
    stage128x64(W0, DMODEL, Wl, tid);
    __syncthreads();

    f32x4 acc[2][8] = {};
    for (int kk = 0; kk < DMODEL; kk += 64) {
        int cur = (kk >> 6) & 1;
        bool more = (kk + 64) < DMODEL;
        short8 an[2][2];
        if (more) {
            stage128x64(W0 + kk + 64, DMODEL, Wl + (cur ^ 1) * 8192, tid);
            an[0][0] = *(const short8*)(Arow0 + kk + 64 + lg * 8);
            an[0][1] = *(const short8*)(Arow0 + kk + 96 + lg * 8);
            an[1][0] = *(const short8*)(Arow1 + kk + 64 + lg * 8);
            an[1][1] = *(const short8*)(Arow1 + kk + 96 + lg * 8);
        }
        const short* Wc = Wl + cur * 8192;
        #pragma unroll
        for (int cg = 0; cg < 8; ++cg) {
            short8 b0 = trd(Wc, cg*16 + lm, lg);
            short8 b1 = trd(Wc, cg*16 + lm, lg + 4);
            #pragma unroll
            for (int rg = 0; rg < 2; ++rg) {
                acc[rg][cg] = MFMA16(a[rg][0], b0, acc[rg][cg]);
                acc[rg][cg] = MFMA16(a[rg][1], b1, acc[rg][cg]);
            }
        }
        if (more) {
            #pragma unroll
            for (int rg = 0; rg < 2; ++rg) { a[rg][0] = an[rg][0]; a[rg][1] = an[rg][1]; }
        }
        __syncthreads();
    }

    if (which < 2) {
        short* outh = which==0 ? qhp : khp;
        #pragma unroll
        for (int rg = 0; rg < 2; ++rg) {
            #pragma unroll
            for (int cg = 0; cg < 8; ++cg) {
                int n = CB0 + cg * 16 + lm;
                int h = n >> 6, d = n & 63;
                #pragma unroll
                for (int r = 0; r < 4; ++r) {
                    int m = RBw + rg * 16 + lg * 4 + r;
                    int bb = m >> 11, s = m & 2047;
                    outh[(size_t)(bb * NHEAD + h) * HSTRIDE + (size_t)s * DQKV + d] =
                        f2bf(acc[rg][cg][r] * scale);
                }
            }
        }
    } else {
        // V output transposed + fragment-permuted: vt[b][h][d][pos(s)]
        int bb = RBw >> 11;
        #pragma unroll
        for (int rg = 0; rg < 2; ++rg) {
            int s0 = (RBw + rg * 16 + lg * 4) & 2047;
            int s6 = s0 & 63;
            // k = 32a+16h+4g (+r) -> pos = 32a+8g+4h (+r)
            int pos = (s0 & ~63) | (s6 & 32) | ((s6 & 12) << 1) | ((s6 & 16) >> 2);
            #pragma unroll
            for (int cg = 0; cg < 8; ++cg) {
                int n = CB0 + cg * 16 + lm;
                int h = n >> 6, d = n & 63;
                short4v pk;
                #pragma unroll
                for (int r = 0; r < 4; ++r) pk[r] = f2bf(acc[rg][cg][r]);
                *(short4v*)(vtp + (size_t)(bb * NHEAD + h) * HSTRIDE
                            + (size_t)d * SEQ + pos) = pk;
            }
        }
    }
}

// ---------- flash attention v8 (FINAL): 128 q/block (32 q/wave), in-register P ----------
// Swapped QK^T, in-register P, fragment-ordered V^T -> one b128 conflict-free B read.
// PV A/B k-ordering: element jj of A (packed P) and B both map to
//   key = kgp*32 + (jj<4 ? lg*4+jj : 16 + lg*4 + (jj-4))
// LDS (shorts): K dbuf at 0 (+cur*4096), V^T dbuf at 8192 (+cur*4096). 32 KB.
// Session-verified negative results (do not re-add):
//  - setprio around MFMA: -20% (r7; barrier-lockstep waves = m190 regime)
//  - 128-key outer tiles: -18% + accuracy drift (r6)
//  - mid-loop barrier / PV-read hoist: -16% (r9)
//  - 64 q/wave at 1 block/CU: -60% (r4, latency-bound)
//  - key-split wave decomposition: accuracy failure ~0.102 (r10/r11, unexplained)
__global__ __launch_bounds__(256, 2) void attn_kernel(
        const short* __restrict__ qh, const short* __restrict__ kh,
        const short* __restrict__ vt, const unsigned long long* __restrict__ mpack,
        short* __restrict__ oh) {
    __shared__ __align__(16) short lds[16384];   // 32 KB
    int tid = threadIdx.x, wave = tid >> 6, lane = tid & 63;
    int lm = lane & 15, lg = lane >> 4;

    // XCD-partition remap: all 512 blocks resident (2/CU); give each XCD 4 bh
    // so its K/V working set (4 x 512 KB = 2 MB) fits the 4 MB per-XCD L2.
    int bid = blockIdx.y * gridDim.x + blockIdx.x;
    int slot = bid >> 3;
    int bh = (bid & 7) * 4 + (slot >> 4);
    int qt = slot & 15;
    int b = bh >> 3;
    int qbase = qt * 128 + wave * 32;

    const short* Kbase = kh + (size_t)bh * HSTRIDE;
    const short* Vtb   = vt + (size_t)bh * HSTRIDE;

    const short8* Qrow = (const short8*)(qh + (size_t)bh * HSTRIDE
                          + (size_t)(qbase + lm) * DQKV);
    short8 aq[2][2];
    aq[0][0] = Qrow[lg];       aq[0][1] = Qrow[lg + 4];
    aq[1][0] = Qrow[128 + lg]; aq[1][1] = Qrow[128 + lg + 4];   // +16 rows

    // wave-uniform mask base: Qg0 = qbase/16 = qt*8 + wave*2
    int mb = __builtin_amdgcn_readfirstlane((b * 128 + qt * 8 + wave * 2) * 512);
    const unsigned long long* mbase = mpack + mb;

    const short one = (short)0x3F80;   // bf16 1.0
    short8 ones8 = {one, one, one, one, one, one, one, one};

    f32x4 o[2][4] = {};
    f32x4 ox[2] = {};

    // prologue: stage tile 0
    stage64x64(Kbase, DQKV, lds, tid);
    stage64x64(Vtb,   SEQ,  lds + 8192, tid);
    __syncthreads();

    for (int kt = 0; kt < SEQ; kt += 64) {
        int cur = (kt >> 6) & 1;
        if (kt + 64 < SEQ) {
            int nxt = cur ^ 1;
            stage64x64(Kbase + (size_t)(kt + 64) * DQKV, DQKV, lds + nxt * 4096, tid);
            stage64x64(Vtb + kt + 64, SEQ, lds + 8192 + nxt * 4096, tid);
        }
        const short* Kc = lds + cur * 4096;
        const short* Vc = lds + 8192 + cur * 4096;
        const unsigned long long* mw = mbase + (kt >> 6) * 16;

        // ---- S^T = K Q^T : sk[qg][kg][r] = S[qbase+qg*16+lm][kt+kg*16+lg*4+r] ----
        f32x4 sk[2][4];
        #pragma unroll
        for (int kg = 0; kg < 4; ++kg) {
            short8 ak0 = trd(Kc, kg * 16 + lm, lg);
            short8 ak1 = trd(Kc, kg * 16 + lm, lg + 4);
            #pragma unroll
            for (int qg = 0; qg < 2; ++qg) {
                f32x4 z{};
                z = MFMA16(ak0, aq[qg][0], z);
                sk[qg][kg] = MFMA16(ak1, aq[qg][1], z);
            }
        }

        // ---- masked exp2 -> packed bf16 A-fragments (pure registers) ----
        // pa8[qg][kgp][jj] = P[q=lm][key = kgp*32 + (jj<4 ? lg*4+jj : 16+lg*4+jj-4)]
        short8 pa8[2][2];
        #pragma unroll
        for (int qg = 0; qg < 2; ++qg) {
            #pragma unroll
            for (int kgp = 0; kgp < 2; ++kgp) {
                float p[8];
                #pragma unroll
                for (int jj = 0; jj < 8; ++jj) {
                    int kg = kgp * 2 + (jj >> 2), r = jj & 3;
                    unsigned long long mword = mw[qg * 512 + kg * 4 + r];
                    float e = __builtin_amdgcn_exp2f(sk[qg][kg][r]);
                    asm("v_cndmask_b32 %0, 0, %1, %2" : "=v"(p[jj]) : "v"(e), "s"(mword));
                }
                int w0, w1, w2, w3;
                asm("v_cvt_pk_bf16_f32 %0, %1, %2" : "=v"(w0) : "v"(p[0]), "v"(p[1]));
                asm("v_cvt_pk_bf16_f32 %0, %1, %2" : "=v"(w1) : "v"(p[2]), "v"(p[3]));
                asm("v_cvt_pk_bf16_f32 %0, %1, %2" : "=v"(w2) : "v"(p[4]), "v"(p[5]));
                asm("v_cvt_pk_bf16_f32 %0, %1, %2" : "=v"(w3) : "v"(p[6]), "v"(p[7]));
                union { int wi[4]; short8 s; } u;
                u.wi[0] = w0; u.wi[1] = w1; u.wi[2] = w2; u.wi[3] = w3;
                pa8[qg][kgp] = u.s;
            }
        }

        // ---- O += P V  (16x16x32; B = ONE b128 read from fragment-ordered V^T) ----
        #pragma unroll
        for (int dt = 0; dt < 4; ++dt) {
            #pragma unroll
            for (int kgp = 0; kgp < 2; ++kgp) {
                short8 bv = trd(Vc, dt * 16 + lm, kgp * 4 + lg);
                o[0][dt] = MFMA16(pa8[0][kgp], bv, o[0][dt]);
                o[1][dt] = MFMA16(pa8[1][kgp], bv, o[1][dt]);
            }
        }
        // rowsum via constant all-ones B fragment (every output col = rowsum)
        #pragma unroll
        for (int qg = 0; qg < 2; ++qg) {
            ox[qg] = MFMA16(pa8[qg][0], ones8, ox[qg]);
            ox[qg] = MFMA16(pa8[qg][1], ones8, ox[qg]);
        }
        __syncthreads();
    }

    // epilogue: normalize, store bf16
    short* ob = oh + (size_t)bh * HSTRIDE;
    #pragma unroll
    for (int qg = 0; qg < 2; ++qg) {
        float rinv[4];
        #pragma unroll
        for (int r = 0; r < 4; ++r) rinv[r] = __builtin_amdgcn_rcpf(ox[qg][r]);
        #pragma unroll
        for (int dt = 0; dt < 4; ++dt) {
            #pragma unroll
            for (int r = 0; r < 4; ++r) {
                ob[(size_t)(qbase + qg * 16 + lg * 4 + r) * DQKV + dt * 16 + lm] =
                    f2bf(o[qg][dt][r] * rinv[r]);
            }
        }
    }
}

// ---------- output projection + residual: 128x64 tiles (32 rows/wave) ----------
__global__ __launch_bounds__(256, 4) void outproj_kernel(
        const short* __restrict__ Ah, const short* __restrict__ Wfct,
        const float* __restrict__ resid, float* __restrict__ out) {
    __shared__ __align__(16) short Wl[2 * 4096];    // 16 KB
    int tid = threadIdx.x, wave = tid >> 6, lane = tid & 63;
    int lm = lane & 15, lg = lane >> 4;
    int CB0 = blockIdx.y * 64;
    int RB = blockIdx.x * 128 + wave * 32;
    const short* W0 = Wfct + (size_t)CB0 * DMODEL;

    int m0 = RB + lm, m1 = RB + 16 + lm;
    size_t rb0 = (size_t)(m0 >> 11) * (NHEAD * HSTRIDE) + (size_t)(m0 & 2047) * DQKV;
    size_t rb1 = (size_t)(m1 >> 11) * (NHEAD * HSTRIDE) + (size_t)(m1 & 2047) * DQKV;

    short8 a[2][2];
    a[0][0] = *(const short8*)(Ah + rb0 + lg * 8);
    a[0][1] = *(const short8*)(Ah + rb0 + 32 + lg * 8);
    a[1][0] = *(const short8*)(Ah + rb1 + lg * 8);
    a[1][1] = *(const short8*)(Ah + rb1 + 32 + lg * 8);
    stage64x64(W0, DMODEL, Wl, tid);
    __syncthreads();

    f32x4 acc[2][4] = {};
    for (int kk = 0; kk < DMODEL; kk += 64) {
        int cur = (kk >> 6) & 1;
        bool more = (kk + 64) < DMODEL;
        short8 an[2][2];
        if (more) {
            stage64x64(W0 + kk + 64, DMODEL, Wl + (cur ^ 1) * 4096, tid);
            size_t hoff = (size_t)((kk >> 6) + 1) * HSTRIDE;
            an[0][0] = *(const short8*)(Ah + rb0 + hoff + lg * 8);
            an[0][1] = *(const short8*)(Ah + rb0 + hoff + 32 + lg * 8);
            an[1][0] = *(const short8*)(Ah + rb1 + hoff + lg * 8);
            an[1][1] = *(const short8*)(Ah + rb1 + hoff + 32 + lg * 8);
        }
        const short* Wc = Wl + cur * 4096;
        #pragma unroll
        for (int cg = 0; cg < 4; ++cg) {
            short8 b0 = trd(Wc, cg*16 + lm, lg);
            short8 b1 = trd(Wc, cg*16 + lm, lg + 4);
            #pragma unroll
            for (int rg = 0; rg < 2; ++rg) {
                acc[rg][cg] = MFMA16(a[rg][0], b0, acc[rg][cg]);
                acc[rg][cg] = MFMA16(a[rg][1], b1, acc[rg][cg]);
            }
        }
        if (more) {
            #pragma unroll
            for (int rg = 0; rg < 2; ++rg) { a[rg][0] = an[rg][0]; a[rg][1] = an[rg][1]; }
        }
        __syncthreads();
    }

    #pragma unroll
    for (int rg = 0; rg < 2; ++rg) {
        #pragma unroll
        for (int cg = 0; cg < 4; ++cg) {
            int n = CB0 + cg * 16 + lm;
            #pragma unroll
            for (int r = 0; r < 4; ++r) {
                int m = RB + rg * 16 + lg * 4 + r;
                size_t idx = (size_t)m * DMODEL + n;
                out[idx] = acc[rg][cg][r] + resid[idx];
            }
        }
    }
}

// ---------- host launch ----------
extern "C" void kernel_launch(void* const* d_in, const int* in_sizes, int n_in,
                              void* d_out, int out_size, void* d_ws, size_t ws_size,
                              hipStream_t stream) {
    const float* q     = (const float*)d_in[0];
    const float* k     = (const float*)d_in[1];
    const float* v     = (const float*)d_in[2];
    const int*   mask  = (const int*)d_in[3];
    const float* Wq    = (const float*)d_in[4];
    const float* Wk    = (const float*)d_in[5];
    const float* Wv    = (const float*)d_in[6];
    const float* Wfc   = (const float*)d_in[7];
    const float* gamma = (const float*)d_in[8];
    const float* beta  = (const float*)d_in[9];
    float* out = (float*)d_out;

    char* ws = (char*)d_ws;
    const size_t SZ_ROWS = (size_t)ROWS * DMODEL * sizeof(short);   // 8 MB
    const size_t SZ_W    = (size_t)DMODEL * DMODEL * sizeof(short); // 512 KB
    short* qn   = (short*)(ws);
    short* kbf  = (short*)(ws + SZ_ROWS);
    short* vbf  = (short*)(ws + 2 * SZ_ROWS);
    short* Wqt  = (short*)(ws + 3 * SZ_ROWS);
    short* Wkt  = (short*)(ws + 3 * SZ_ROWS + SZ_W);
    short* Wvt  = (short*)(ws + 3 * SZ_ROWS + 2 * SZ_W);
    short* Wfct = (short*)(ws + 3 * SZ_ROWS + 3 * SZ_W);
    short* qhb  = (short*)(ws + 3 * SZ_ROWS + 4 * SZ_W);
    short* khb  = (short*)(ws + 4 * SZ_ROWS + 4 * SZ_W);
    short* vtb  = (short*)(ws + 5 * SZ_ROWS + 4 * SZ_W);
    unsigned long long* mpack = (unsigned long long*)(ws + 6 * SZ_ROWS + 4 * SZ_W); // 2 MB
    short* aout = qn;    // qn dead after proj

    prep_all_kernel<<<dim3(10496), 256, 0, stream>>>(
        q, k, v, gamma, beta, mask, Wq, Wk, Wv, Wfc,
        qn, kbf, vbf, mpack, Wqt, Wkt, Wvt, Wfct);

    proj_qkv_kernel<<<dim3(ROWS / 128, 12), 256, 0, stream>>>(
        qn, kbf, vbf, Wqt, Wkt, Wvt, qhb, khb, vtb);

    attn_kernel<<<dim3(SEQ / 128, BH), 256, 0, stream>>>(qhb, khb, vtb, mpack, aout);

    outproj_kernel<<<dim3(ROWS / 128, DMODEL / 64), 256, 0, stream>>>(aout, Wfct, q, out);
}

// Round 13
// 241.305 us; speedup vs baseline: 1.0836x; 1.0108x over previous
//
#include <hip/hip_runtime.h>

// ---------- constants ----------
#define BATCH 4
#define SEQ   2048
#define NHEAD 8
#define DQKV  64
#define DMODEL 512
#define ROWS  (BATCH*SEQ)          // 8192
#define BH    (BATCH*NHEAD)        // 32
#define HSTRIDE (SEQ*DQKV)         // 131072 elements per (b,h)

using f32x4  = __attribute__((ext_vector_type(4))) float;
using short8 = __attribute__((ext_vector_type(8))) short;
using short4v = __attribute__((ext_vector_type(4))) short;

#define MFMA16(a,b,c) __builtin_amdgcn_mfma_f32_16x16x32_bf16((a),(b),(c),0,0,0)

__device__ __forceinline__ short f2bf(float f) {
    unsigned u = __float_as_uint(f);
    u += 0x7FFFu + ((u >> 16) & 1u);
    return (short)(u >> 16);
}

// async global->LDS 16B DMA (LDS dst = waveBase + lane*16)
__device__ __forceinline__ void gl2lds16(const short* g, short* l) {
    __builtin_amdgcn_global_load_lds(
        (__attribute__((address_space(1))) void*)g,
        (__attribute__((address_space(3))) void*)l, 16, 0, 0);
}

// stage a 64-row x 64-short tile (8KB), XOR chunk-swizzled, via DMA.
// swizzle applied in GLOBAL source so LDS write order stays linear.
__device__ __forceinline__ void stage64x64(const short* g0, int gstride, short* lt, int t) {
    #pragma unroll
    for (int p = 0; p < 2; ++p) {
        int o = p * 2048 + t * 8;          // shorts; per-lane 16B, linear
        int row = o >> 6;
        int c = ((o >> 3) & 7) ^ (row & 7);
        gl2lds16(g0 + (size_t)row * gstride + c * 8, lt + o);
    }
}
// 128-row variant (16KB)
__device__ __forceinline__ void stage128x64(const short* g0, int gstride, short* lt, int t) {
    stage64x64(g0, gstride, lt, t);
    stage64x64(g0 + (size_t)64 * gstride, gstride, lt + 4096, t);
}

// read logical 16B chunk (row, c) from a swizzled 64-short-stride tile
__device__ __forceinline__ short8 trd(const short* t, int row, int c) {
    return *(const short8*)(t + row * 64 + ((c ^ (row & 7)) << 3));
}

// ---------- fused prep: cast k/v | LN(q) | W transpose-cast ----------
// (maskpack moved into proj_mask_kernel so its 67 MB HBM read overlaps proj compute)
// 1-D grid, block ranges:
//   [0,4096)     cast k (first 2048) / v (next 2048) -> bf16
//   [4096,6144)  LayerNorm(q) -> bf16
//   [6144,6400)  W[k][n] -> Wt[n][k] bf16 (4 weights, 64x64 tiles)
__global__ __launch_bounds__(256) void prep_all_kernel(
        const float* __restrict__ q, const float* __restrict__ k,
        const float* __restrict__ v, const float* __restrict__ gamma,
        const float* __restrict__ beta,
        const float* __restrict__ W0in, const float* __restrict__ W1in,
        const float* __restrict__ W2in, const float* __restrict__ W3in,
        short* __restrict__ qn, short* __restrict__ kb, short* __restrict__ vb,
        short* __restrict__ T0, short* __restrict__ T1,
        short* __restrict__ T2, short* __restrict__ T3) {
    __shared__ short tile[64 * 68];
    int bid = blockIdx.x;
    int tid = threadIdx.x;
    if (bid < 4096) {
        // ---- cast k / v -> bf16
        const float* src = (bid < 2048) ? k : v;
        short* dst = (bid < 2048) ? kb : vb;
        size_t i = (size_t)(bid & 2047) * 2048 + (size_t)tid * 8;
        float4 a = *(const float4*)(src + i);
        float4 c = *(const float4*)(src + i + 4);
        short8 o;
        o[0]=f2bf(a.x); o[1]=f2bf(a.y); o[2]=f2bf(a.z); o[3]=f2bf(a.w);
        o[4]=f2bf(c.x); o[5]=f2bf(c.y); o[6]=f2bf(c.z); o[7]=f2bf(c.w);
        *(short8*)(dst + i) = o;
    } else if (bid < 6144) {
        // ---- LayerNorm(q) -> bf16, one row per wave
        int wave = tid >> 6, lane = tid & 63;
        int row  = (bid - 4096) * 4 + wave;
        const float4* qr = (const float4*)(q + (size_t)row * DMODEL);
        float4 x0 = qr[lane * 2];
        float4 x1 = qr[lane * 2 + 1];
        float s  = x0.x + x0.y + x0.z + x0.w + x1.x + x1.y + x1.z + x1.w;
        float s2 = x0.x*x0.x + x0.y*x0.y + x0.z*x0.z + x0.w*x0.w
                 + x1.x*x1.x + x1.y*x1.y + x1.z*x1.z + x1.w*x1.w;
        #pragma unroll
        for (int m = 1; m < 64; m <<= 1) {
            s  += __shfl_xor(s,  m);
            s2 += __shfl_xor(s2, m);
        }
        float mu  = s * (1.0f / DMODEL);
        float var = s2 * (1.0f / DMODEL) - mu * mu;
        float rstd = rsqrtf(var + 1e-6f);
        const float4* g = (const float4*)gamma;
        const float4* be = (const float4*)beta;
        float4 g0 = g[lane*2], g1 = g[lane*2+1];
        float4 b0 = be[lane*2], b1 = be[lane*2+1];
        short8 o;
        o[0] = f2bf((x0.x - mu) * rstd * g0.x + b0.x);
        o[1] = f2bf((x0.y - mu) * rstd * g0.y + b0.y);
        o[2] = f2bf((x0.z - mu) * rstd * g0.z + b0.z);
        o[3] = f2bf((x0.w - mu) * rstd * g0.w + b0.w);
        o[4] = f2bf((x1.x - mu) * rstd * g1.x + b1.x);
        o[5] = f2bf((x1.y - mu) * rstd * g1.y + b1.y);
        o[6] = f2bf((x1.z - mu) * rstd * g1.z + b1.z);
        o[7] = f2bf((x1.w - mu) * rstd * g1.w + b1.w);
        ((short8*)(qn + (size_t)row * DMODEL))[lane] = o;
    } else {
        // ---- W transpose-cast: 64x64 tile per block
        int b4 = bid - 6144;           // [0,256)
        int w = b4 >> 6, ti = (b4 >> 3) & 7, tj = b4 & 7;
        const float* W = w==0 ? W0in : w==1 ? W1in : w==2 ? W2in : W3in;
        short* T = w==0 ? T0 : w==1 ? T1 : w==2 ? T2 : T3;
        #pragma unroll
        for (int p = 0; p < 4; ++p) {
            int idx = tid + p * 256;
            int kl = idx >> 4, c4 = idx & 15;
            float4 f = *(const float4*)(W + (size_t)(tj*64 + kl) * DMODEL + ti*64 + c4*4);
            short4v sv; sv[0]=f2bf(f.x); sv[1]=f2bf(f.y); sv[2]=f2bf(f.z); sv[3]=f2bf(f.w);
            *(short4v*)(tile + kl*68 + c4*4) = sv;
        }
        __syncthreads();
        #pragma unroll
        for (int p = 0; p < 4; ++p) {
            int idx = tid + p * 256;
            int nl = idx >> 4, kseg = idx & 15;
            short4v sv;
            #pragma unroll
            for (int i = 0; i < 4; ++i) sv[i] = tile[(kseg*4 + i)*68 + nl];
            *(short4v*)(T + (size_t)(ti*64 + nl) * DMODEL + tj*64 + kseg*4) = sv;
        }
    }
}

// ---------- fused QKV projection + maskpack: 1-D grid 4864 ----------
// bid [0,768): proj 128x128 tiles (dispatched first -> holds CUs; long blocks).
// bid [768,4864): maskpack blocks (short, HBM-bound) fill spare CU slots so the
// 67 MB mask read overlaps proj's compute instead of serializing in prep.
// V^T stored in PV-fragment order: within each 64-key block,
//   key k = 32a+16h+4g+r  ->  pos = 32a+8g+4h+r
// so attn's PV B-operand is ONE contiguous 16B chunk per lane (b128, conflict-free).
__global__ __launch_bounds__(256, 4) void proj_mask_kernel(
        const short* __restrict__ qn, const short* __restrict__ kb,
        const short* __restrict__ vb,
        const short* __restrict__ Wqt, const short* __restrict__ Wkt,
        const short* __restrict__ Wvt,
        const int* __restrict__ mask, unsigned long long* __restrict__ mp,
        short* __restrict__ qhp, short* __restrict__ khp, short* __restrict__ vtp) {
    __shared__ __align__(16) short Wl[2 * 8192];     // 32 KB
    int bid = blockIdx.x;
    int tid = threadIdx.x;
    if (bid >= 768) {
        // ---- maskpack: word idx = (((b*128+Qg)*32+w64)*4+kg)*4+r,
        //      bit l (=16*lg+lm) = mask[Qg*16+lm][w64*64+kg*16+lg*4+r]
        int gw = (bid - 768) * 4 + (tid >> 6);
        int lane = tid & 63;
        int lm = lane & 15, lg = lane >> 4;
        int w64 = gw & 31;
        int Qg  = (gw >> 5) & 127;
        int b   = gw >> 12;
        const int* src = mask + ((size_t)b * SEQ + Qg * 16 + lm) * SEQ + w64 * 64 + lg * 4;
        unsigned long long* d = mp + (size_t)gw * 16;
        #pragma unroll
        for (int kg = 0; kg < 4; ++kg) {
            int4 vv = *(const int4*)(src + kg * 16);
            unsigned long long w0 = __ballot(vv.x != 0);
            unsigned long long w1 = __ballot(vv.y != 0);
            unsigned long long w2 = __ballot(vv.z != 0);
            unsigned long long w3 = __ballot(vv.w != 0);
            if (lane == 0) {
                *(ulonglong2*)(d + kg*4)     = make_ulonglong2(w0, w1);
                *(ulonglong2*)(d + kg*4 + 2) = make_ulonglong2(w2, w3);
            }
        }
        return;
    }
    int wave = tid >> 6, lane = tid & 63;
    int lm = lane & 15, lg = lane >> 4;
    int by = bid >> 6, bx = bid & 63;        // == old (blockIdx.y, blockIdx.x)
    int which = by >> 2;
    int CB0 = (by & 3) * 128;
    const short* A  = which==0 ? qn  : which==1 ? kb  : vb;
    const short* Wt = which==0 ? Wqt : which==1 ? Wkt : Wvt;
    // Q gets 1/sqrt(64) * log2(e) folded in (attention uses exp2)
    float scale = which==0 ? 0.18033688f : 1.0f;

    int RBw = bx * 128 + wave * 32;
    const short* Arow0 = A + (size_t)(RBw + lm) * DMODEL;
    const short* Arow1 = A + (size_t)(RBw + 16 + lm) * DMODEL;
    const short* W0 = Wt + (size_t)CB0 * DMODEL;

    short8 a[2][2];
    a[0][0] = *(const short8*)(Arow0 + lg * 8);
    a[0][1] = *(const short8*)(Arow0 + 32 + lg * 8);
    a[1][0] = *(const short8*)(Arow1 + lg * 8);
    a[1][1] = *(const short8*)(Arow1 + 32 + lg * 8);
    stage128x64(W0, DMODEL, Wl, tid);
    __syncthreads();

    f32x4 acc[2][8] = {};
    for (int kk = 0; kk < DMODEL; kk += 64) {
        int cur = (kk >> 6) & 1;
        bool more = (kk + 64) < DMODEL;
        short8 an[2][2];
        if (more) {
            stage128x64(W0 + kk + 64, DMODEL, Wl + (cur ^ 1) * 8192, tid);
            an[0][0] = *(const short8*)(Arow0 + kk + 64 + lg * 8);
            an[0][1] = *(const short8*)(Arow0 + kk + 96 + lg * 8);
            an[1][0] = *(const short8*)(Arow1 + kk + 64 + lg * 8);
            an[1][1] = *(const short8*)(Arow1 + kk + 96 + lg * 8);
        }
        const short* Wc = Wl + cur * 8192;
        #pragma unroll
        for (int cg = 0; cg < 8; ++cg) {
            short8 b0 = trd(Wc, cg*16 + lm, lg);
            short8 b1 = trd(Wc, cg*16 + lm, lg + 4);
            #pragma unroll
            for (int rg = 0; rg < 2; ++rg) {
                acc[rg][cg] = MFMA16(a[rg][0], b0, acc[rg][cg]);
                acc[rg][cg] = MFMA16(a[rg][1], b1, acc[rg][cg]);
            }
        }
        if (more) {
            #pragma unroll
            for (int rg = 0; rg < 2; ++rg) { a[rg][0] = an[rg][0]; a[rg][1] = an[rg][1]; }
        }
        __syncthreads();
    }

    if (which < 2) {
        short* outh = which==0 ? qhp : khp;
        #pragma unroll
        for (int rg = 0; rg < 2; ++rg) {
            #pragma unroll
            for (int cg = 0; cg < 8; ++cg) {
                int n = CB0 + cg * 16 + lm;
                int h = n >> 6, d = n & 63;
                #pragma unroll
                for (int r = 0; r < 4; ++r) {
                    int m = RBw + rg * 16 + lg * 4 + r;
                    int bb = m >> 11, s = m & 2047;
                    outh[(size_t)(bb * NHEAD + h) * HSTRIDE + (size_t)s * DQKV + d] =
                        f2bf(acc[rg][cg][r] * scale);
                }
            }
        }
    } else {
        // V output transposed + fragment-permuted: vt[b][h][d][pos(s)]
        int bb = RBw >> 11;
        #pragma unroll
        for (int rg = 0; rg < 2; ++rg) {
            int s0 = (RBw + rg * 16 + lg * 4) & 2047;
            int s6 = s0 & 63;
            // k = 32a+16h+4g (+r) -> pos = 32a+8g+4h (+r)
            int pos = (s0 & ~63) | (s6 & 32) | ((s6 & 12) << 1) | ((s6 & 16) >> 2);
            #pragma unroll
            for (int cg = 0; cg < 8; ++cg) {
                int n = CB0 + cg * 16 + lm;
                int h = n >> 6, d = n & 63;
                short4v pk;
                #pragma unroll
                for (int r = 0; r < 4; ++r) pk[r] = f2bf(acc[rg][cg][r]);
                *(short4v*)(vtp + (size_t)(bb * NHEAD + h) * HSTRIDE
                            + (size_t)d * SEQ + pos) = pk;
            }
        }
    }
}

// ---------- flash attention v8 (verified 55us): 128 q/block (32 q/wave) ----------
// Swapped QK^T, in-register P, fragment-ordered V^T -> one b128 conflict-free B read.
// PV A/B k-ordering: element jj of A (packed P) and B both map to
//   key = kgp*32 + (jj<4 ? lg*4+jj : 16 + lg*4 + (jj-4))
// LDS (shorts): K dbuf at 0 (+cur*4096), V^T dbuf at 8192 (+cur*4096). 32 KB.
// Session-verified negative results (do not re-add):
//  - setprio around MFMA: -20% (r7; barrier-lockstep waves = m190 regime)
//  - 128-key outer tiles: -18% + accuracy drift (r6)
//  - mid-loop barrier / PV-read hoist: -16% (r9)
//  - 64 q/wave at 1 block/CU: -60% (r4, latency-bound)
//  - key-split wave decomposition: accuracy failure ~0.102 (r10/r11, unexplained)
__global__ __launch_bounds__(256, 2) void attn_kernel(
        const short* __restrict__ qh, const short* __restrict__ kh,
        const short* __restrict__ vt, const unsigned long long* __restrict__ mpack,
        short* __restrict__ oh) {
    __shared__ __align__(16) short lds[16384];   // 32 KB
    int tid = threadIdx.x, wave = tid >> 6, lane = tid & 63;
    int lm = lane & 15, lg = lane >> 4;

    // XCD-partition remap: all 512 blocks resident (2/CU); give each XCD 4 bh
    // so its K/V working set (4 x 512 KB = 2 MB) fits the 4 MB per-XCD L2.
    int bid = blockIdx.y * gridDim.x + blockIdx.x;
    int slot = bid >> 3;
    int bh = (bid & 7) * 4 + (slot >> 4);
    int qt = slot & 15;
    int b = bh >> 3;
    int qbase = qt * 128 + wave * 32;

    const short* Kbase = kh + (size_t)bh * HSTRIDE;
    const short* Vtb   = vt + (size_t)bh * HSTRIDE;

    const short8* Qrow = (const short8*)(qh + (size_t)bh * HSTRIDE
                          + (size_t)(qbase + lm) * DQKV);
    short8 aq[2][2];
    aq[0][0] = Qrow[lg];       aq[0][1] = Qrow[lg + 4];
    aq[1][0] = Qrow[128 + lg]; aq[1][1] = Qrow[128 + lg + 4];   // +16 rows

    // wave-uniform mask base: Qg0 = qbase/16 = qt*8 + wave*2
    int mb = __builtin_amdgcn_readfirstlane((b * 128 + qt * 8 + wave * 2) * 512);
    const unsigned long long* mbase = mpack + mb;

    const short one = (short)0x3F80;   // bf16 1.0
    short8 ones8 = {one, one, one, one, one, one, one, one};

    f32x4 o[2][4] = {};
    f32x4 ox[2] = {};

    // prologue: stage tile 0
    stage64x64(Kbase, DQKV, lds, tid);
    stage64x64(Vtb,   SEQ,  lds + 8192, tid);
    __syncthreads();

    for (int kt = 0; kt < SEQ; kt += 64) {
        int cur = (kt >> 6) & 1;
        if (kt + 64 < SEQ) {
            int nxt = cur ^ 1;
            stage64x64(Kbase + (size_t)(kt + 64) * DQKV, DQKV, lds + nxt * 4096, tid);
            stage64x64(Vtb + kt + 64, SEQ, lds + 8192 + nxt * 4096, tid);
        }
        const short* Kc = lds + cur * 4096;
        const short* Vc = lds + 8192 + cur * 4096;
        const unsigned long long* mw = mbase + (kt >> 6) * 16;

        // ---- S^T = K Q^T : sk[qg][kg][r] = S[qbase+qg*16+lm][kt+kg*16+lg*4+r] ----
        f32x4 sk[2][4];
        #pragma unroll
        for (int kg = 0; kg < 4; ++kg) {
            short8 ak0 = trd(Kc, kg * 16 + lm, lg);
            short8 ak1 = trd(Kc, kg * 16 + lm, lg + 4);
            #pragma unroll
            for (int qg = 0; qg < 2; ++qg) {
                f32x4 z{};
                z = MFMA16(ak0, aq[qg][0], z);
                sk[qg][kg] = MFMA16(ak1, aq[qg][1], z);
            }
        }

        // ---- masked exp2 -> packed bf16 A-fragments (pure registers) ----
        // pa8[qg][kgp][jj] = P[q=lm][key = kgp*32 + (jj<4 ? lg*4+jj : 16+lg*4+jj-4)]
        short8 pa8[2][2];
        #pragma unroll
        for (int qg = 0; qg < 2; ++qg) {
            #pragma unroll
            for (int kgp = 0; kgp < 2; ++kgp) {
                float p[8];
                #pragma unroll
                for (int jj = 0; jj < 8; ++jj) {
                    int kg = kgp * 2 + (jj >> 2), r = jj & 3;
                    unsigned long long mword = mw[qg * 512 + kg * 4 + r];
                    float e = __builtin_amdgcn_exp2f(sk[qg][kg][r]);
                    asm("v_cndmask_b32 %0, 0, %1, %2" : "=v"(p[jj]) : "v"(e), "s"(mword));
                }
                int w0, w1, w2, w3;
                asm("v_cvt_pk_bf16_f32 %0, %1, %2" : "=v"(w0) : "v"(p[0]), "v"(p[1]));
                asm("v_cvt_pk_bf16_f32 %0, %1, %2" : "=v"(w1) : "v"(p[2]), "v"(p[3]));
                asm("v_cvt_pk_bf16_f32 %0, %1, %2" : "=v"(w2) : "v"(p[4]), "v"(p[5]));
                asm("v_cvt_pk_bf16_f32 %0, %1, %2" : "=v"(w3) : "v"(p[6]), "v"(p[7]));
                union { int wi[4]; short8 s; } u;
                u.wi[0] = w0; u.wi[1] = w1; u.wi[2] = w2; u.wi[3] = w3;
                pa8[qg][kgp] = u.s;
            }
        }

        // ---- O += P V  (16x16x32; B = ONE b128 read from fragment-ordered V^T) ----
        #pragma unroll
        for (int dt = 0; dt < 4; ++dt) {
            #pragma unroll
            for (int kgp = 0; kgp < 2; ++kgp) {
                short8 bv = trd(Vc, dt * 16 + lm, kgp * 4 + lg);
                o[0][dt] = MFMA16(pa8[0][kgp], bv, o[0][dt]);
                o[1][dt] = MFMA16(pa8[1][kgp], bv, o[1][dt]);
            }
        }
        // rowsum via constant all-ones B fragment (every output col = rowsum)
        #pragma unroll
        for (int qg = 0; qg < 2; ++qg) {
            ox[qg] = MFMA16(pa8[qg][0], ones8, ox[qg]);
            ox[qg] = MFMA16(pa8[qg][1], ones8, ox[qg]);
        }
        __syncthreads();
    }

    // epilogue: normalize, store bf16
    short* ob = oh + (size_t)bh * HSTRIDE;
    #pragma unroll
    for (int qg = 0; qg < 2; ++qg) {
        float rinv[4];
        #pragma unroll
        for (int r = 0; r < 4; ++r) rinv[r] = __builtin_amdgcn_rcpf(ox[qg][r]);
        #pragma unroll
        for (int dt = 0; dt < 4; ++dt) {
            #pragma unroll
            for (int r = 0; r < 4; ++r) {
                ob[(size_t)(qbase + qg * 16 + lg * 4 + r) * DQKV + dt * 16 + lm] =
                    f2bf(o[qg][dt][r] * rinv[r]);
            }
        }
    }
}

// ---------- output projection + residual: 128x64 tiles (32 rows/wave) ----------
__global__ __launch_bounds__(256, 4) void outproj_kernel(
        const short* __restrict__ Ah, const short* __restrict__ Wfct,
        const float* __restrict__ resid, float* __restrict__ out) {
    __shared__ __align__(16) short Wl[2 * 4096];    // 16 KB
    int tid = threadIdx.x, wave = tid >> 6, lane = tid & 63;
    int lm = lane & 15, lg = lane >> 4;
    int CB0 = blockIdx.y * 64;
    int RB = blockIdx.x * 128 + wave * 32;
    const short* W0 = Wfct + (size_t)CB0 * DMODEL;

    int m0 = RB + lm, m1 = RB + 16 + lm;
    size_t rb0 = (size_t)(m0 >> 11) * (NHEAD * HSTRIDE) + (size_t)(m0 & 2047) * DQKV;
    size_t rb1 = (size_t)(m1 >> 11) * (NHEAD * HSTRIDE) + (size_t)(m1 & 2047) * DQKV;

    short8 a[2][2];
    a[0][0] = *(const short8*)(Ah + rb0 + lg * 8);
    a[0][1] = *(const short8*)(Ah + rb0 + 32 + lg * 8);
    a[1][0] = *(const short8*)(Ah + rb1 + lg * 8);
    a[1][1] = *(const short8*)(Ah + rb1 + 32 + lg * 8);
    stage64x64(W0, DMODEL, Wl, tid);
    __syncthreads();

    f32x4 acc[2][4] = {};
    for (int kk = 0; kk < DMODEL; kk += 64) {
        int cur = (kk >> 6) & 1;
        bool more = (kk + 64) < DMODEL;
        short8 an[2][2];
        if (more) {
            stage64x64(W0 + kk + 64, DMODEL, Wl + (cur ^ 1) * 4096, tid);
            size_t hoff = (size_t)((kk >> 6) + 1) * HSTRIDE;
            an[0][0] = *(const short8*)(Ah + rb0 + hoff + lg * 8);
            an[0][1] = *(const short8*)(Ah + rb0 + hoff + 32 + lg * 8);
            an[1][0] = *(const short8*)(Ah + rb1 + hoff + lg * 8);
            an[1][1] = *(const short8*)(Ah + rb1 + hoff + 32 + lg * 8);
        }
        const short* Wc = Wl + cur * 4096;
        #pragma unroll
        for (int cg = 0; cg < 4; ++cg) {
            short8 b0 = trd(Wc, cg*16 + lm, lg);
            short8 b1 = trd(Wc, cg*16 + lm, lg + 4);
            #pragma unroll
            for (int rg = 0; rg < 2; ++rg) {
                acc[rg][cg] = MFMA16(a[rg][0], b0, acc[rg][cg]);
                acc[rg][cg] = MFMA16(a[rg][1], b1, acc[rg][cg]);
            }
        }
        if (more) {
            #pragma unroll
            for (int rg = 0; rg < 2; ++rg) { a[rg][0] = an[rg][0]; a[rg][1] = an[rg][1]; }
        }
        __syncthreads();
    }

    #pragma unroll
    for (int rg = 0; rg < 2; ++rg) {
        #pragma unroll
        for (int cg = 0; cg < 4; ++cg) {
            int n = CB0 + cg * 16 + lm;
            #pragma unroll
            for (int r = 0; r < 4; ++r) {
                int m = RB + rg * 16 + lg * 4 + r;
                size_t idx = (size_t)m * DMODEL + n;
                out[idx] = acc[rg][cg][r] + resid[idx];
            }
        }
    }
}

// ---------- host launch ----------
extern "C" void kernel_launch(void* const* d_in, const int* in_sizes, int n_in,
                              void* d_out, int out_size, void* d_ws, size_t ws_size,
                              hipStream_t stream) {
    const float* q     = (const float*)d_in[0];
    const float* k     = (const float*)d_in[1];
    const float* v     = (const float*)d_in[2];
    const int*   mask  = (const int*)d_in[3];
    const float* Wq    = (const float*)d_in[4];
    const float* Wk    = (const float*)d_in[5];
    const float* Wv    = (const float*)d_in[6];
    const float* Wfc   = (const float*)d_in[7];
    const float* gamma = (const float*)d_in[8];
    const float* beta  = (const float*)d_in[9];
    float* out = (float*)d_out;

    char* ws = (char*)d_ws;
    const size_t SZ_ROWS = (size_t)ROWS * DMODEL * sizeof(short);   // 8 MB
    const size_t SZ_W    = (size_t)DMODEL * DMODEL * sizeof(short); // 512 KB
    short* qn   = (short*)(ws);
    short* kbf  = (short*)(ws + SZ_ROWS);
    short* vbf  = (short*)(ws + 2 * SZ_ROWS);
    short* Wqt  = (short*)(ws + 3 * SZ_ROWS);
    short* Wkt  = (short*)(ws + 3 * SZ_ROWS + SZ_W);
    short* Wvt  = (short*)(ws + 3 * SZ_ROWS + 2 * SZ_W);
    short* Wfct = (short*)(ws + 3 * SZ_ROWS + 3 * SZ_W);
    short* qhb  = (short*)(ws + 3 * SZ_ROWS + 4 * SZ_W);
    short* khb  = (short*)(ws + 4 * SZ_ROWS + 4 * SZ_W);
    short* vtb  = (short*)(ws + 5 * SZ_ROWS + 4 * SZ_W);
    unsigned long long* mpack = (unsigned long long*)(ws + 6 * SZ_ROWS + 4 * SZ_W); // 2 MB
    short* aout = qn;    // qn dead after proj

    prep_all_kernel<<<dim3(6400), 256, 0, stream>>>(
        q, k, v, gamma, beta, Wq, Wk, Wv, Wfc,
        qn, kbf, vbf, Wqt, Wkt, Wvt, Wfct);

    proj_mask_kernel<<<dim3(768 + 4096), 256, 0, stream>>>(
        qn, kbf, vbf, Wqt, Wkt, Wvt, mask, mpack, qhb, khb, vtb);

    attn_kernel<<<dim3(SEQ / 128, BH), 256, 0, stream>>>(qhb, khb, vtb, mpack, aout);

    outproj_kernel<<<dim3(ROWS / 128, DMODEL / 64), 256, 0, stream>>>(aout, Wfct, q, out);
}